// Round 7
// baseline (261.785 us; speedup 1.0000x reference)
//
#include <hip/hip_runtime.h>

typedef __bf16 bf16x8 __attribute__((ext_vector_type(8)));
typedef float f32x4 __attribute__((ext_vector_type(4)));

typedef const unsigned int __attribute__((address_space(1)))* gas_p;
typedef unsigned int __attribute__((address_space(3)))* las_p;

__device__ __forceinline__ void gload_lds16(const void* g, void* l) {
  __builtin_amdgcn_global_load_lds((gas_p)g, (las_p)l, 16, 0, 0);
}

__device__ __forceinline__ unsigned short f2bf(float f) {
  union { float f; unsigned int u; } x; x.f = f;
  unsigned int r = x.u + 0x7fffu + ((x.u >> 16) & 1u);
  return (unsigned short)(r >> 16);
}
__device__ __forceinline__ float elu1(float x) {
  return x > 0.f ? x + 1.f : __expf(x);
}
__device__ __forceinline__ f32x4 mfma16(bf16x8 a, bf16x8 b, f32x4 c) {
  return __builtin_amdgcn_mfma_f32_16x16x32_bf16(a, b, c, 0, 0, 0);
}
__device__ __forceinline__ unsigned int cvtpk(float lo, float hi) {
  unsigned int r;
  asm("v_cvt_pk_bf16_f32 %0, %1, %2" : "=v"(r) : "v"(lo), "v"(hi));
  return r;
}

#define BAR() __builtin_amdgcn_s_barrier()
#define VMW12() asm volatile("s_waitcnt vmcnt(12)" ::: "memory")
#define VMW8() asm volatile("s_waitcnt vmcnt(8)" ::: "memory")
#define VMW6() asm volatile("s_waitcnt vmcnt(6)" ::: "memory")
#define VMW4() asm volatile("s_waitcnt vmcnt(4)" ::: "memory")
#define VMW0() asm volatile("s_waitcnt vmcnt(0)" ::: "memory")
#define LGKM0() do { asm volatile("s_waitcnt lgkmcnt(0)" ::: "memory"); \
                     __builtin_amdgcn_sched_barrier(0); } while (0)

// ---------------- weight transpose/convert ----------------

__global__ __launch_bounds__(256) void k_cvt_t(const float* __restrict__ w,
                                               unsigned short* __restrict__ wT,
                                               int R, int Cc) {
  __shared__ float t[32][33];
  const int j0 = blockIdx.x * 32, i0 = blockIdx.y * 32;
  const int tx = threadIdx.x & 31, ty = threadIdx.x >> 5;
#pragma unroll
  for (int k = 0; k < 4; ++k)
    t[ty + 8 * k][tx] = w[(size_t)(i0 + ty + 8 * k) * Cc + j0 + tx];
  __syncthreads();
#pragma unroll
  for (int k = 0; k < 4; ++k)
    wT[(size_t)(j0 + ty + 8 * k) * R + i0 + tx] = f2bf(t[tx][ty + 8 * k]);
}

// ---------------- qkv GEMM: A = x (f32) reg-staged + in-loop cvt, ring-4 B via DMA ----
// LDS: 4 A-slots + 4 B-slots of [256 rows][32 K] bf16 (16 KiB each) = 128 KiB.
// Pair p (32-K half-tile) lives in slot p&3. Per tile t (pairs 2t,2t+1):
//  P0: reads(2t,rh0); B-DMA(2t+3);                LGKM0; BAR; MFMA
//  P1: reads(2t,rh1); VMW8; writeA(2t+1); issueA(2t+3); LGKM0; BAR; MFMA
//  P2: reads(2t+1,rh0); B-DMA(2t+4);              LGKM0; BAR; MFMA
//  P3: reads(2t+1,rh1); VMW8; writeA(2t+2); issueA(2t+4); LGKM0; BAR; MFMA
// vmcnt: steady 14 outstanding -> VMW(8) retires {B(pair), A-regs(pair)} exactly.
// Swizzle: read col ^= ((row>>1)&3)<<3; A ds_write dest swizzled; B source pre-swizzled.

__global__ __launch_bounds__(512, 2) void k_gemmq(
    const float* __restrict__ X, const unsigned short* __restrict__ BT,
    unsigned short* __restrict__ qb, unsigned short* __restrict__ kT,
    unsigned short* __restrict__ vT) {
  extern __shared__ unsigned short lds[];
  unsigned short* Asb = lds;           // 4 slots x 8192 elems
  unsigned short* Bsb = lds + 32768;

  const int tid = threadIdx.x, lane = tid & 63, wave = tid >> 6;
  const int wm = wave >> 2, wn = wave & 3;
  int bid = blockIdx.x;
  { const int cpx = (int)gridDim.x >> 3; bid = (bid & 7) * cpx + (bid >> 3); }
  const int bx = bid % 12, by = bid / 12;
  const size_t bm0 = (size_t)by << 8, bn0 = (size_t)bx << 8;

  // staging: thread covers rows {srow, srow+128}, 8 elems at col8, within [256][32]
  const int srow = (wave << 4) + (lane >> 2);
  const int col8 = (lane & 3) << 3;
  const int swkey = ((srow >> 1) & 3) << 3;
  const unsigned short* Bg0 = BT + (bn0 + srow) * 1024 + (col8 ^ swkey);
  const float* Xg0 = X + (bm0 + srow) * 1024 + col8;
  const int lws = wave << 9;
  unsigned short* Al0 = Asb + srow * 32 + (col8 ^ swkey);

  auto stageB = [&](int pair) {
    const unsigned short* g_ = Bg0 + (pair << 5);
    unsigned short* l_ = Bsb + ((pair & 3) << 13) + lws;
    gload_lds16(g_, l_);
    gload_lds16(g_ + 128 * 1024, l_ + 4096);
  };

  float4 aX0, aX1, aX2, aX3, aY0, aY1, aY2, aY3;
  auto issueAX = [&](int pair) {
    const float* g_ = Xg0 + (pair << 5);
    aX0 = *(const float4*)g_;                  aX1 = *(const float4*)(g_ + 4);
    aX2 = *(const float4*)(g_ + 128 * 1024);   aX3 = *(const float4*)(g_ + 128 * 1024 + 4);
  };
  auto issueAY = [&](int pair) {
    const float* g_ = Xg0 + (pair << 5);
    aY0 = *(const float4*)g_;                  aY1 = *(const float4*)(g_ + 4);
    aY2 = *(const float4*)(g_ + 128 * 1024);   aY3 = *(const float4*)(g_ + 128 * 1024 + 4);
  };
  auto writeAX = [&](int pair) {
    uint4 w0, w1;
    w0.x = cvtpk(aX0.x, aX0.y); w0.y = cvtpk(aX0.z, aX0.w);
    w0.z = cvtpk(aX1.x, aX1.y); w0.w = cvtpk(aX1.z, aX1.w);
    w1.x = cvtpk(aX2.x, aX2.y); w1.y = cvtpk(aX2.z, aX2.w);
    w1.z = cvtpk(aX3.x, aX3.y); w1.w = cvtpk(aX3.z, aX3.w);
    unsigned short* l_ = Al0 + ((pair & 3) << 13);
    *(uint4*)l_ = w0;
    *(uint4*)(l_ + 128 * 32) = w1;
  };
  auto writeAY = [&](int pair) {
    uint4 w0, w1;
    w0.x = cvtpk(aY0.x, aY0.y); w0.y = cvtpk(aY0.z, aY0.w);
    w0.z = cvtpk(aY1.x, aY1.y); w0.w = cvtpk(aY1.z, aY1.w);
    w1.x = cvtpk(aY2.x, aY2.y); w1.y = cvtpk(aY2.z, aY2.w);
    w1.z = cvtpk(aY3.x, aY3.y); w1.w = cvtpk(aY3.z, aY3.w);
    unsigned short* l_ = Al0 + ((pair & 3) << 13);
    *(uint4*)l_ = w0;
    *(uint4*)(l_ + 128 * 32) = w1;
  };

  const int q8 = ((lane >> 4) << 3) ^ (((lane >> 1) & 3) << 3);
  const int ar_base = (wm << 7) + (lane & 15);
  const int br_base = (wn << 6) + (lane & 15);

  f32x4 acc[8][4] = {};  // [rh*4+mi][n]

  // prologue: issue order [A0(4), B0(2), B1(2)] -> VMW4 retires A0;
  // then [A1(4), B2(2), A2(4)] -> VMW12 retires B0; leaves [B1,A1,B2,A2]=12.
  issueAY(0);
  stageB(0);
  stageB(1);
  VMW4();
  writeAY(0);
  issueAX(1);
  stageB(2);
  issueAY(2);
  VMW12();
  LGKM0();
  BAR();

#pragma unroll
  for (int t = 0; t < 16; ++t) {
    const int s0 = (2 * t) & 3, s1 = (2 * t + 1) & 3;
    bf16x8 af[4], bfr[4];

    // ---- P0 ----
#pragma unroll
    for (int mi = 0; mi < 4; ++mi)
      af[mi] = *(const bf16x8*)&Asb[(s0 << 13) + ((ar_base + mi * 16) << 5) + q8];
#pragma unroll
    for (int n = 0; n < 4; ++n)
      bfr[n] = *(const bf16x8*)&Bsb[(s0 << 13) + ((br_base + n * 16) << 5) + q8];
    if (t <= 14) stageB(2 * t + 3);
    LGKM0();
    BAR();
    __builtin_amdgcn_s_setprio(1);
#pragma unroll
    for (int mi = 0; mi < 4; ++mi)
#pragma unroll
      for (int n = 0; n < 4; ++n) acc[mi][n] = mfma16(af[mi], bfr[n], acc[mi][n]);
    __builtin_amdgcn_s_setprio(0);

    // ---- P1 ----
#pragma unroll
    for (int mi = 0; mi < 4; ++mi)
      af[mi] = *(const bf16x8*)&Asb[(s0 << 13) + ((ar_base + 64 + mi * 16) << 5) + q8];
    if (t <= 14) { VMW8(); } else { VMW0(); }
    writeAX(2 * t + 1);
    if (t <= 14) issueAX(2 * t + 3);
    LGKM0();
    BAR();
    __builtin_amdgcn_s_setprio(1);
#pragma unroll
    for (int mi = 0; mi < 4; ++mi)
#pragma unroll
      for (int n = 0; n < 4; ++n) acc[4 + mi][n] = mfma16(af[mi], bfr[n], acc[4 + mi][n]);
    __builtin_amdgcn_s_setprio(0);

    // ---- P2 ----
#pragma unroll
    for (int mi = 0; mi < 4; ++mi)
      af[mi] = *(const bf16x8*)&Asb[(s1 << 13) + ((ar_base + mi * 16) << 5) + q8];
#pragma unroll
    for (int n = 0; n < 4; ++n)
      bfr[n] = *(const bf16x8*)&Bsb[(s1 << 13) + ((br_base + n * 16) << 5) + q8];
    if (t <= 13) stageB(2 * t + 4);
    LGKM0();
    BAR();
    __builtin_amdgcn_s_setprio(1);
#pragma unroll
    for (int mi = 0; mi < 4; ++mi)
#pragma unroll
      for (int n = 0; n < 4; ++n) acc[mi][n] = mfma16(af[mi], bfr[n], acc[mi][n]);
    __builtin_amdgcn_s_setprio(0);

    // ---- P3 ----
#pragma unroll
    for (int mi = 0; mi < 4; ++mi)
      af[mi] = *(const bf16x8*)&Asb[(s1 << 13) + ((ar_base + 64 + mi * 16) << 5) + q8];
    if (t <= 13) { VMW8(); } else if (t == 14) { VMW6(); }
    if (t <= 14) writeAY(2 * t + 2);
    if (t <= 13) issueAY(2 * t + 4);
    LGKM0();
    BAR();
    __builtin_amdgcn_s_setprio(1);
#pragma unroll
    for (int mi = 0; mi < 4; ++mi)
#pragma unroll
      for (int n = 0; n < 4; ++n) acc[4 + mi][n] = mfma16(af[mi], bfr[n], acc[4 + mi][n]);
    __builtin_amdgcn_s_setprio(0);
  }
  VMW0();

  // ---- epilogue: elu+1 on q,k; scatter k,v to [bh][d][n] ----
  const int rbase = (int)bm0 + (wm << 7) + ((lane >> 4) << 2);
  const int cbase = (int)bn0 + (wn << 6) + (lane & 15);
  const int reg3 = (int)(bn0 >> 10);  // 0=q 1=k 2=v, uniform per block
#pragma unroll
  for (int m = 0; m < 8; ++m) {
    const int rb = rbase + m * 16;
#pragma unroll
    for (int n = 0; n < 4; ++n) {
      const int col = cbase + n * 16;
      if (reg3 == 0) {
#pragma unroll
        for (int i = 0; i < 4; ++i)
          qb[(size_t)(rb + i) * 1024 + col] = f2bf(elu1(acc[m][n][i]));
      } else {
        const int jc = col & 1023, h = jc >> 6, d = jc & 63;
        const int b_ = rb >> 12, n_ = rb & 4095;
        union { unsigned short u[4]; uint2 q; } pk;
        if (reg3 == 1) {
#pragma unroll
          for (int i = 0; i < 4; ++i) pk.u[i] = f2bf(elu1(acc[m][n][i]));
        } else {
#pragma unroll
          for (int i = 0; i < 4; ++i) pk.u[i] = f2bf(acc[m][n][i]);
        }
        unsigned short* dst = (reg3 == 1) ? kT : vT;
        *(uint2*)(dst + ((size_t)((b_ * 16 + h) * 64 + d) * 4096 + n_)) = pk.q;
      }
    }
  }
}

// ---------------- proj GEMM: ring-4 all-DMA, single barrier per phase ----------------

__global__ __launch_bounds__(512, 2) void k_gemmp(
    const unsigned short* __restrict__ A, const unsigned short* __restrict__ BT,
    const float* __restrict__ bias, float* __restrict__ out) {
  extern __shared__ unsigned short lds[];
  unsigned short* Asb = lds;
  unsigned short* Bsb = lds + 32768;

  const int tid = threadIdx.x, lane = tid & 63, wave = tid >> 6;
  const int wm = wave >> 2, wn = wave & 3;
  int bid = blockIdx.x;
  { const int cpx = (int)gridDim.x >> 3; bid = (bid & 7) * cpx + (bid >> 3); }
  const int bx = bid % 4, by = bid / 4;
  const size_t bm0 = (size_t)by << 8, bn0 = (size_t)bx << 8;

  const int srow = (wave << 4) + (lane >> 2);
  const int gscol = ((lane & 3) << 3) ^ (((srow >> 1) & 3) << 3);
  const unsigned short* Ag0 = A + (bm0 + srow) * 1024 + gscol;
  const unsigned short* Bg0 = BT + (bn0 + srow) * 1024 + gscol;
  const int lws = wave << 9;

  auto stageA = [&](int slot, int kt, int kh) {
    const unsigned short* g_ = Ag0 + (kt << 6) + (kh << 5);
    unsigned short* l_ = Asb + (slot << 13) + lws;
    gload_lds16(g_, l_);
    gload_lds16(g_ + 128 * 1024, l_ + 4096);
  };
  auto stageB = [&](int slot, int kt, int kh) {
    const unsigned short* g_ = Bg0 + (kt << 6) + (kh << 5);
    unsigned short* l_ = Bsb + (slot << 13) + lws;
    gload_lds16(g_, l_);
    gload_lds16(g_ + 128 * 1024, l_ + 4096);
  };

  const int q8 = ((lane >> 4) << 3) ^ (((lane >> 1) & 3) << 3);
  const int ar_base = (wm << 7) + (lane & 15);
  const int br_base = (wn << 6) + (lane & 15);

  f32x4 acc[8][4] = {};

  stageA(0, 0, 0); stageB(0, 0, 0);
  stageA(1, 0, 1); stageB(1, 0, 1);
  stageA(2, 1, 0); stageB(2, 1, 0);
  VMW8();
  BAR();

#pragma unroll
  for (int t = 0; t < 16; ++t) {
    const int s0 = (2 * t) & 3, s1 = (2 * t + 1) & 3;
    const int sA = (2 * t + 3) & 3, sB = (2 * t + 4) & 3;
    const int t1 = t + 1, t2 = t + 2;
    bf16x8 af[4], bfr[4];

#pragma unroll
    for (int mi = 0; mi < 4; ++mi)
      af[mi] = *(const bf16x8*)&Asb[(s0 << 13) + ((ar_base + mi * 16) << 5) + q8];
#pragma unroll
    for (int n = 0; n < 4; ++n)
      bfr[n] = *(const bf16x8*)&Bsb[(s0 << 13) + ((br_base + n * 16) << 5) + q8];
    if (t < 15) stageA(sA, t1, 1);
    LGKM0();
    BAR();
    __builtin_amdgcn_s_setprio(1);
#pragma unroll
    for (int mi = 0; mi < 4; ++mi)
#pragma unroll
      for (int n = 0; n < 4; ++n) acc[mi][n] = mfma16(af[mi], bfr[n], acc[mi][n]);
    __builtin_amdgcn_s_setprio(0);

#pragma unroll
    for (int mi = 0; mi < 4; ++mi)
      af[mi] = *(const bf16x8*)&Asb[(s0 << 13) + ((ar_base + 64 + mi * 16) << 5) + q8];
    if (t < 15) stageB(sA, t1, 1);
    if (t < 15) { VMW8(); } else { VMW4(); }
    LGKM0();
    BAR();
    __builtin_amdgcn_s_setprio(1);
#pragma unroll
    for (int mi = 0; mi < 4; ++mi)
#pragma unroll
      for (int n = 0; n < 4; ++n) acc[4 + mi][n] = mfma16(af[mi], bfr[n], acc[4 + mi][n]);
    __builtin_amdgcn_s_setprio(0);

#pragma unroll
    for (int mi = 0; mi < 4; ++mi)
      af[mi] = *(const bf16x8*)&Asb[(s1 << 13) + ((ar_base + mi * 16) << 5) + q8];
#pragma unroll
    for (int n = 0; n < 4; ++n)
      bfr[n] = *(const bf16x8*)&Bsb[(s1 << 13) + ((br_base + n * 16) << 5) + q8];
    if (t < 14) stageA(sB, t2, 0);
    LGKM0();
    BAR();
    __builtin_amdgcn_s_setprio(1);
#pragma unroll
    for (int mi = 0; mi < 4; ++mi)
#pragma unroll
      for (int n = 0; n < 4; ++n) acc[mi][n] = mfma16(af[mi], bfr[n], acc[mi][n]);
    __builtin_amdgcn_s_setprio(0);

#pragma unroll
    for (int mi = 0; mi < 4; ++mi)
      af[mi] = *(const bf16x8*)&Asb[(s1 << 13) + ((ar_base + 64 + mi * 16) << 5) + q8];
    if (t < 14) stageB(sB, t2, 0);
    if (t < 14) { VMW8(); } else if (t == 14) { VMW4(); }
    LGKM0();
    BAR();
    __builtin_amdgcn_s_setprio(1);
#pragma unroll
    for (int mi = 0; mi < 4; ++mi)
#pragma unroll
      for (int n = 0; n < 4; ++n) acc[4 + mi][n] = mfma16(af[mi], bfr[n], acc[4 + mi][n]);
    __builtin_amdgcn_s_setprio(0);
  }
  VMW0();

  const int rbase = (int)bm0 + (wm << 7) + ((lane >> 4) << 2);
  const int cbase = (int)bn0 + (wn << 6) + (lane & 15);
#pragma unroll
  for (int n = 0; n < 4; ++n) {
    const int col = cbase + n * 16;
    const float bc = bias[col];
#pragma unroll
    for (int m = 0; m < 8; ++m) {
      const int rb = rbase + m * 16;
#pragma unroll
      for (int i = 0; i < 4; ++i)
        out[(size_t)(rb + i) * 1024 + col] = acc[m][n][i] + bc;
    }
  }
}

// ---------------- kv partial (+ fused sum_k via ones-column) ----------------

__global__ __launch_bounds__(256) void k_kvpart(const unsigned short* __restrict__ kT,
                                                const unsigned short* __restrict__ vT,
                                                float* __restrict__ kvp,
                                                float* __restrict__ sumkp) {
  __shared__ unsigned short Ks[64 * 64];
  __shared__ unsigned short Vs[64 * 64];
  const int blk = blockIdx.x;
  const int bh = blk >> 3, ch = blk & 7;
  const int tid = threadIdx.x, lane = tid & 63, wave = tid >> 6;
  const unsigned short* kb = kT + (size_t)bh * 64 * 4096;
  const unsigned short* vb = vT + (size_t)bh * 64 * 4096;
  const int n0 = ch * 512;
  const int lrow = lane >> 3;
  const int lcolz = (((lane & 7) ^ (lane >> 3)) << 3);
  f32x4 acc[5] = {};

  bf16x8 ones_frag;
  {
    unsigned short o = ((lane & 15) == 0) ? (unsigned short)0x3F80 : (unsigned short)0;
    union { unsigned short u[8]; bf16x8 v; } c;
#pragma unroll
    for (int i = 0; i < 8; ++i) c.u[i] = o;
    ones_frag = c.v;
  }

  const int rxor = (lane & 7) << 3;
  const int col0 = (((lane >> 4) << 3)) ^ rxor;
  const int col1 = ((32 + ((lane >> 4) << 3))) ^ rxor;

  for (int ks = 0; ks < 512; ks += 64) {
    __syncthreads();
#pragma unroll
    for (int i = 0; i < 2; ++i) {
      const int c = i * 4 + wave;
      gload_lds16(kb + (size_t)(c * 8 + lrow) * 4096 + n0 + ks + lcolz, &Ks[c * 512]);
      gload_lds16(vb + (size_t)(c * 8 + lrow) * 4096 + n0 + ks + lcolz, &Vs[c * 512]);
    }
    __syncthreads();
    const int ar = wave * 16 + (lane & 15);
#pragma unroll
    for (int kk = 0; kk < 2; ++kk) {
      const int co = kk ? col1 : col0;
      bf16x8 a = *(const bf16x8*)&Ks[ar * 64 + co];
#pragma unroll
      for (int n = 0; n < 4; ++n) {
        bf16x8 bv = *(const bf16x8*)&Vs[(n * 16 + (lane & 15)) * 64 + co];
        acc[n] = mfma16(a, bv, acc[n]);
      }
      acc[4] = mfma16(a, ones_frag, acc[4]);
    }
  }
  float* dst = kvp + (size_t)blk * 64 * 64;
  const int d0 = wave * 16 + ((lane >> 4) << 2);
#pragma unroll
  for (int n = 0; n < 4; ++n)
#pragma unroll
    for (int i = 0; i < 4; ++i)
      dst[(d0 + i) * 64 + n * 16 + (lane & 15)] = acc[n][i];
  if ((lane & 15) == 0) {
#pragma unroll
    for (int i = 0; i < 4; ++i) sumkp[(size_t)blk * 64 + d0 + i] = acc[4][i];
  }
}

// ---------------- kv reduce ----------------

__global__ __launch_bounds__(256) void k_kvred(const float* __restrict__ kvp,
                                               const float* __restrict__ sumkp,
                                               unsigned short* __restrict__ kvsk) {
  const int bh = blockIdx.x, tid = threadIdx.x;
  const float* src = kvp + (size_t)bh * 8 * 4096;
  unsigned short* dst = kvsk + (size_t)bh * 80 * 64;
#pragma unroll
  for (int it = 0; it < 16; ++it) {
    const int idx = tid + it * 256;
    const int e = idx >> 6, d = idx & 63;
    float s = 0.f;
#pragma unroll
    for (int c = 0; c < 8; ++c) s += src[c * 4096 + d * 64 + e];
    dst[idx] = f2bf(s);
  }
#pragma unroll
  for (int it = 0; it < 4; ++it) {
    const int idx = tid + it * 256;
    const int e2 = idx >> 6, d = idx & 63;
    float v = 0.f;
    if (e2 == 0) {
#pragma unroll
      for (int c = 0; c < 8; ++c) v += sumkp[(size_t)(bh * 8 + c) * 64 + d];
    }
    dst[64 * 64 + idx] = f2bf(v);
  }
}

// ---------------- numerator/denominator/divide ----------------

__global__ __launch_bounds__(256) void k_numer(const unsigned short* __restrict__ qb,
                                               const unsigned short* __restrict__ kvsk,
                                               unsigned short* __restrict__ yb) {
  __shared__ unsigned short Bs[80 * 64];
  const int bh = blockIdx.y;
  const int b = bh >> 4, h = bh & 15;
  const int n0 = blockIdx.x << 7;
  const int tid = threadIdx.x, lane = tid & 63, wave = tid >> 6;
  {
    const uint4* src = (const uint4*)(kvsk + (size_t)bh * 80 * 64);
    uint4* dst = (uint4*)Bs;
    for (int i = tid; i < 640; i += 256) dst[i ^ ((i >> 3) & 7)] = src[i];
  }
  __syncthreads();

  const int ko = (lane >> 4) << 3;
  const int rx = (lane & 7) << 3;
  f32x4 acc[2][5] = {};
  const unsigned short* qrow =
      qb + (size_t)(b * 4096 + n0 + wave * 32 + (lane & 15)) * 1024 + h * 64;
#pragma unroll
  for (int kk = 0; kk < 2; ++kk) {
    bf16x8 a[2], bb[5];
#pragma unroll
    for (int m = 0; m < 2; ++m)
      a[m] = *(const bf16x8*)(qrow + (size_t)m * 16 * 1024 + ko + kk * 32);
#pragma unroll
    for (int n = 0; n < 5; ++n)
      bb[n] = *(const bf16x8*)&Bs[(n * 16 + (lane & 15)) * 64 + ((ko + kk * 32) ^ rx)];
#pragma unroll
    for (int m = 0; m < 2; ++m)
#pragma unroll
      for (int n = 0; n < 5; ++n)
        acc[m][n] = mfma16(a[m], bb[n], acc[m][n]);
  }

  const int rbase = b * 4096 + n0 + wave * 32 + ((lane >> 4) << 2);
#pragma unroll
  for (int m = 0; m < 2; ++m) {
    f32x4 inv;
#pragma unroll
    for (int i = 0; i < 4; ++i) {
      float den = __shfl(acc[m][4][i], lane & 48);
      inv[i] = __builtin_amdgcn_rcpf(den);
    }
#pragma unroll
    for (int n = 0; n < 4; ++n) {
      const int col = h * 64 + n * 16 + (lane & 15);
#pragma unroll
      for (int i = 0; i < 4; ++i)
        yb[(size_t)(rbase + m * 16 + i) * 1024 + col] = f2bf(acc[m][n][i] * inv[i]);
    }
  }
}

// ---------------- launch ----------------

extern "C" void kernel_launch(void* const* d_in, const int* in_sizes, int n_in,
                              void* d_out, int out_size, void* d_ws, size_t ws_size,
                              hipStream_t stream) {
  const float* x = (const float*)d_in[0];
  const float* w_qkv = (const float*)d_in[1];
  const float* w_proj = (const float*)d_in[2];
  const float* b_proj = (const float*)d_in[3];
  float* out = (float*)d_out;
  char* ws = (char*)d_ws;

  unsigned short* yb = (unsigned short*)(ws);                   // 33,554,432 B
  unsigned short* wqkvT = (unsigned short*)(ws + 33554432);     //  6,291,456 B (reused as sumkp)
  unsigned short* wprojT = (unsigned short*)(ws + 39845888);    //  2,097,152 B
  unsigned short* qb = (unsigned short*)(ws + 41943040);        // 33,554,432 B
  unsigned short* kT = (unsigned short*)(ws + 75497472);        // 33,554,432 B
  unsigned short* vT = (unsigned short*)(ws + 109051904);       // 33,554,432 B
  float* kvp = (float*)(ws + 142606336);                        //  8,388,608 B
  unsigned short* kvsk = (unsigned short*)(ws + 151011328);     //    655,360 B
  float* sumkp = (float*)wqkvT;            // wqkvT dead after GEMM1 (512*64*4 B)

  k_cvt_t<<<dim3(96, 32), 256, 0, stream>>>(w_qkv, wqkvT, 1024, 3072);
  k_cvt_t<<<dim3(32, 32), 256, 0, stream>>>(w_proj, wprojT, 1024, 1024);
  k_gemmq<<<768, 512, 131072, stream>>>(x, wqkvT, qb, kT, vT);
  k_kvpart<<<512, 256, 0, stream>>>(kT, vT, kvp, sumkp);
  k_kvred<<<64, 256, 0, stream>>>(kvp, sumkp, kvsk);
  k_numer<<<dim3(32, 64), 256, 0, stream>>>(qb, kvsk, yb);
  k_gemmp<<<256, 512, 131072, stream>>>(yb, wprojT, b_proj, out);
}

// Round 8
// 227.037 us; speedup vs baseline: 1.1530x; 1.1530x over previous
//
#include <hip/hip_runtime.h>

typedef __bf16 bf16x8 __attribute__((ext_vector_type(8)));
typedef float f32x4 __attribute__((ext_vector_type(4)));

typedef const unsigned int __attribute__((address_space(1)))* gas_p;
typedef unsigned int __attribute__((address_space(3)))* las_p;

__device__ __forceinline__ void gload_lds16(const void* g, void* l) {
  __builtin_amdgcn_global_load_lds((gas_p)g, (las_p)l, 16, 0, 0);
}

__device__ __forceinline__ unsigned short f2bf(float f) {
  union { float f; unsigned int u; } x; x.f = f;
  unsigned int r = x.u + 0x7fffu + ((x.u >> 16) & 1u);
  return (unsigned short)(r >> 16);
}
__device__ __forceinline__ float elu1(float x) {
  return x > 0.f ? x + 1.f : __expf(x);
}
__device__ __forceinline__ f32x4 mfma16(bf16x8 a, bf16x8 b, f32x4 c) {
  return __builtin_amdgcn_mfma_f32_16x16x32_bf16(a, b, c, 0, 0, 0);
}

#define BAR() __builtin_amdgcn_s_barrier()
#define VMW0() asm volatile("s_waitcnt vmcnt(0)" ::: "memory")
#define LGKM0() do { asm volatile("s_waitcnt lgkmcnt(0)" ::: "memory"); \
                     __builtin_amdgcn_sched_barrier(0); } while (0)

// ---------------- converts ----------------

__global__ __launch_bounds__(256) void k_cvt_x(const float* __restrict__ x,
                                               unsigned short* __restrict__ xb, int n) {
  int i = (blockIdx.x * 256 + threadIdx.x) * 4;
  const int stride = gridDim.x * 256 * 4;
  for (; i < n; i += stride) {
    float4 v = *(const float4*)(x + i);
    union { unsigned short u[4]; uint2 q; } pk;
    pk.u[0] = f2bf(v.x); pk.u[1] = f2bf(v.y); pk.u[2] = f2bf(v.z); pk.u[3] = f2bf(v.w);
    *(uint2*)(xb + i) = pk.q;
  }
}

__global__ __launch_bounds__(256) void k_cvt_t(const float* __restrict__ w,
                                               unsigned short* __restrict__ wT,
                                               int R, int Cc) {
  __shared__ float t[32][33];
  const int j0 = blockIdx.x * 32, i0 = blockIdx.y * 32;
  const int tx = threadIdx.x & 31, ty = threadIdx.x >> 5;
#pragma unroll
  for (int k = 0; k < 4; ++k)
    t[ty + 8 * k][tx] = w[(size_t)(i0 + ty + 8 * k) * Cc + j0 + tx];
  __syncthreads();
#pragma unroll
  for (int k = 0; k < 4; ++k)
    wT[(size_t)(j0 + ty + 8 * k) * R + i0 + tx] = f2bf(t[tx][ty + 8 * k]);
}

// ---------------- qkv GEMM: 256x256 tile, ring-2 32-K pairs, 64 KiB LDS, 2 blk/CU ------
// LDS: per operand 2 slots of [256 rows][32 K] bf16 (16 KiB). pair p in slot p&1.
// Per pair: phase a {reads(12), stage p+1 (4 DMA), lgkm0, bar, MFMA rh0};
//           phase b {reads(4), vmcnt0, lgkm0, bar, MFMA rh1}.
// Swizzle: read col ^= ((row>>1)&3)<<3 elems; B/A DMA source col pre-swizzled (rule 21).

__global__ __launch_bounds__(512, 2) void k_gemmq(
    const unsigned short* __restrict__ A, const unsigned short* __restrict__ BT,
    unsigned short* __restrict__ qb, unsigned short* __restrict__ kT,
    unsigned short* __restrict__ vT) {
  extern __shared__ unsigned short lds[];
  unsigned short* Asb = lds;            // 2 slots x 8192 elems
  unsigned short* Bsb = lds + 16384;    // 2 slots x 8192 elems

  const int tid = threadIdx.x, lane = tid & 63, wave = tid >> 6;
  const int wm = wave >> 2, wn = wave & 3;
  int bid = blockIdx.x;
  { const int cpx = (int)gridDim.x >> 3; bid = (bid & 7) * cpx + (bid >> 3); }
  const int bx = bid % 12, by = bid / 12;
  const size_t bm0 = (size_t)by << 8, bn0 = (size_t)bx << 8;

  const int srow = (wave << 4) + (lane >> 2);
  const int gscol = ((lane & 3) << 3) ^ (((srow >> 1) & 3) << 3);
  const unsigned short* Ag0 = A + (bm0 + srow) * 1024 + gscol;
  const unsigned short* Bg0 = BT + (bn0 + srow) * 1024 + gscol;
  const int lws = wave << 9;

  auto stageA = [&](int pair) {
    const unsigned short* g_ = Ag0 + (pair << 5);
    unsigned short* l_ = Asb + ((pair & 1) << 13) + lws;
    gload_lds16(g_, l_);
    gload_lds16(g_ + 128 * 1024, l_ + 4096);
  };
  auto stageB = [&](int pair) {
    const unsigned short* g_ = Bg0 + (pair << 5);
    unsigned short* l_ = Bsb + ((pair & 1) << 13) + lws;
    gload_lds16(g_, l_);
    gload_lds16(g_ + 128 * 1024, l_ + 4096);
  };

  const int q8 = ((lane >> 4) << 3) ^ (((lane >> 1) & 3) << 3);
  const int ar_base = (wm << 7) + (lane & 15);
  const int br_base = (wn << 6) + (lane & 15);

  f32x4 acc[8][4] = {};  // [rh*4+mi][n]

  stageA(0); stageB(0);
  VMW0();
  BAR();

#define QKV_PAIR(P, SOFF)                                                             \
  {                                                                                   \
    bf16x8 af[4], bfr[4];                                                             \
    _Pragma("unroll") for (int mi = 0; mi < 4; ++mi)                                  \
        af[mi] = *(const bf16x8*)&Asb[(SOFF) + ((ar_base + mi * 16) << 5) + q8];      \
    _Pragma("unroll") for (int n = 0; n < 4; ++n)                                     \
        bfr[n] = *(const bf16x8*)&Bsb[(SOFF) + ((br_base + n * 16) << 5) + q8];       \
    if ((P) < 31) { stageA((P) + 1); stageB((P) + 1); }                               \
    LGKM0();                                                                          \
    BAR();                                                                            \
    __builtin_amdgcn_s_setprio(1);                                                    \
    _Pragma("unroll") for (int mi = 0; mi < 4; ++mi)                                  \
        _Pragma("unroll") for (int n = 0; n < 4; ++n)                                 \
            acc[mi][n] = mfma16(af[mi], bfr[n], acc[mi][n]);                          \
    __builtin_amdgcn_s_setprio(0);                                                    \
    _Pragma("unroll") for (int mi = 0; mi < 4; ++mi)                                  \
        af[mi] = *(const bf16x8*)&Asb[(SOFF) + ((ar_base + 64 + mi * 16) << 5) + q8]; \
    VMW0();                                                                           \
    LGKM0();                                                                          \
    BAR();                                                                            \
    __builtin_amdgcn_s_setprio(1);                                                    \
    _Pragma("unroll") for (int mi = 0; mi < 4; ++mi)                                  \
        _Pragma("unroll") for (int n = 0; n < 4; ++n)                                 \
            acc[4 + mi][n] = mfma16(af[mi], bfr[n], acc[4 + mi][n]);                  \
    __builtin_amdgcn_s_setprio(0);                                                    \
  }

  for (int p = 0; p < 32; p += 2) {
    QKV_PAIR(p, 0)
    QKV_PAIR(p + 1, 8192)
  }
#undef QKV_PAIR

  // ---- epilogue: elu+1 on q,k; scatter k,v to [bh][d][n] ----
  const int rbase = (int)bm0 + (wm << 7) + ((lane >> 4) << 2);
  const int cbase = (int)bn0 + (wn << 6) + (lane & 15);
  const int reg3 = (int)(bn0 >> 10);  // 0=q 1=k 2=v, uniform per block
#pragma unroll
  for (int m = 0; m < 8; ++m) {
    const int rb = rbase + m * 16;
#pragma unroll
    for (int n = 0; n < 4; ++n) {
      const int col = cbase + n * 16;
      if (reg3 == 0) {
#pragma unroll
        for (int i = 0; i < 4; ++i)
          qb[(size_t)(rb + i) * 1024 + col] = f2bf(elu1(acc[m][n][i]));
      } else {
        const int jc = col & 1023, h = jc >> 6, d = jc & 63;
        const int b_ = rb >> 12, n_ = rb & 4095;
        union { unsigned short u[4]; uint2 q; } pk;
        if (reg3 == 1) {
#pragma unroll
          for (int i = 0; i < 4; ++i) pk.u[i] = f2bf(elu1(acc[m][n][i]));
        } else {
#pragma unroll
          for (int i = 0; i < 4; ++i) pk.u[i] = f2bf(acc[m][n][i]);
        }
        unsigned short* dst = (reg3 == 1) ? kT : vT;
        *(uint2*)(dst + ((size_t)((b_ * 16 + h) * 64 + d) * 4096 + n_)) = pk.q;
      }
    }
  }
}

// ---------------- proj GEMM: 128x256 tile, ring-2 32-K pairs, 48 KiB LDS, 2 blk/CU ----
// grid 512 = 128 by x 4 bx. 8 waves (2m x 4n), wave tile 64x64, acc[4][4].

__global__ __launch_bounds__(512, 2) void k_gemmp(
    const unsigned short* __restrict__ A, const unsigned short* __restrict__ BT,
    const float* __restrict__ bias, float* __restrict__ out) {
  extern __shared__ unsigned short lds[];
  unsigned short* Asb = lds;            // 2 slots x 4096 elems ([128][32])
  unsigned short* Bsb = lds + 8192;     // 2 slots x 8192 elems ([256][32])

  const int tid = threadIdx.x, lane = tid & 63, wave = tid >> 6;
  const int wm = wave >> 2, wn = wave & 3;
  int bid = blockIdx.x;
  { const int cpx = (int)gridDim.x >> 3; bid = (bid & 7) * cpx + (bid >> 3); }
  const int bx = bid % 4, by = bid / 4;
  const size_t bm0 = (size_t)by << 7, bn0 = (size_t)bx << 8;

  const int srow = (wave << 4) + (lane >> 2);
  const int gscol = ((lane & 3) << 3) ^ (((srow >> 1) & 3) << 3);
  const unsigned short* Ag0 = A + (bm0 + srow) * 1024 + gscol;
  const unsigned short* Bg0 = BT + (bn0 + srow) * 1024 + gscol;

  auto stageA = [&](int pair) {  // 128 rows: 1 load/thread
    gload_lds16(Ag0 + (pair << 5), Asb + ((pair & 1) << 12) + (wave << 9));
  };
  auto stageB = [&](int pair) {  // 256 rows: 2 loads/thread
    const unsigned short* g_ = Bg0 + (pair << 5);
    unsigned short* l_ = Bsb + ((pair & 1) << 13) + (wave << 9);
    gload_lds16(g_, l_);
    gload_lds16(g_ + 128 * 1024, l_ + 4096);
  };

  const int q8 = ((lane >> 4) << 3) ^ (((lane >> 1) & 3) << 3);
  const int ar_base = (wm << 6) + (lane & 15);
  const int br_base = (wn << 6) + (lane & 15);

  f32x4 acc[4][4] = {};

  stageA(0); stageB(0);
  VMW0();
  BAR();

#define PRJ_PAIR(P, SA, SB)                                                           \
  {                                                                                   \
    bf16x8 af[4], bfr[4];                                                             \
    _Pragma("unroll") for (int mi = 0; mi < 4; ++mi)                                  \
        af[mi] = *(const bf16x8*)&Asb[(SA) + ((ar_base + mi * 16) << 5) + q8];        \
    _Pragma("unroll") for (int n = 0; n < 4; ++n)                                     \
        bfr[n] = *(const bf16x8*)&Bsb[(SB) + ((br_base + n * 16) << 5) + q8];         \
    if ((P) < 31) { stageA((P) + 1); stageB((P) + 1); }                               \
    VMW0();                                                                           \
    LGKM0();                                                                          \
    BAR();                                                                            \
    __builtin_amdgcn_s_setprio(1);                                                    \
    _Pragma("unroll") for (int mi = 0; mi < 4; ++mi)                                  \
        _Pragma("unroll") for (int n = 0; n < 4; ++n)                                 \
            acc[mi][n] = mfma16(af[mi], bfr[n], acc[mi][n]);                          \
    __builtin_amdgcn_s_setprio(0);                                                    \
  }

  for (int p = 0; p < 32; p += 2) {
    PRJ_PAIR(p, 0, 0)
    PRJ_PAIR(p + 1, 4096, 8192)
  }
#undef PRJ_PAIR

  const int rbase = (int)bm0 + (wm << 6) + ((lane >> 4) << 2);
  const int cbase = (int)bn0 + (wn << 6) + (lane & 15);
#pragma unroll
  for (int n = 0; n < 4; ++n) {
    const int col = cbase + n * 16;
    const float bc = bias[col];
#pragma unroll
    for (int m = 0; m < 4; ++m) {
      const int rb = rbase + m * 16;
#pragma unroll
      for (int i = 0; i < 4; ++i)
        out[(size_t)(rb + i) * 1024 + col] = acc[m][n][i] + bc;
    }
  }
}

// ---------------- kv partial (+ fused sum_k via ones-column) ----------------

__global__ __launch_bounds__(256) void k_kvpart(const unsigned short* __restrict__ kT,
                                                const unsigned short* __restrict__ vT,
                                                float* __restrict__ kvp,
                                                float* __restrict__ sumkp) {
  __shared__ unsigned short Ks[64 * 64];
  __shared__ unsigned short Vs[64 * 64];
  const int blk = blockIdx.x;
  const int bh = blk >> 3, ch = blk & 7;
  const int tid = threadIdx.x, lane = tid & 63, wave = tid >> 6;
  const unsigned short* kb = kT + (size_t)bh * 64 * 4096;
  const unsigned short* vb = vT + (size_t)bh * 64 * 4096;
  const int n0 = ch * 512;
  const int lrow = lane >> 3;
  const int lcolz = (((lane & 7) ^ (lane >> 3)) << 3);
  f32x4 acc[5] = {};

  bf16x8 ones_frag;
  {
    unsigned short o = ((lane & 15) == 0) ? (unsigned short)0x3F80 : (unsigned short)0;
    union { unsigned short u[8]; bf16x8 v; } c;
#pragma unroll
    for (int i = 0; i < 8; ++i) c.u[i] = o;
    ones_frag = c.v;
  }

  const int rxor = (lane & 7) << 3;
  const int col0 = (((lane >> 4) << 3)) ^ rxor;
  const int col1 = ((32 + ((lane >> 4) << 3))) ^ rxor;

  for (int ks = 0; ks < 512; ks += 64) {
    __syncthreads();
#pragma unroll
    for (int i = 0; i < 2; ++i) {
      const int c = i * 4 + wave;
      gload_lds16(kb + (size_t)(c * 8 + lrow) * 4096 + n0 + ks + lcolz, &Ks[c * 512]);
      gload_lds16(vb + (size_t)(c * 8 + lrow) * 4096 + n0 + ks + lcolz, &Vs[c * 512]);
    }
    __syncthreads();
    const int ar = wave * 16 + (lane & 15);
#pragma unroll
    for (int kk = 0; kk < 2; ++kk) {
      const int co = kk ? col1 : col0;
      bf16x8 a = *(const bf16x8*)&Ks[ar * 64 + co];
#pragma unroll
      for (int n = 0; n < 4; ++n) {
        bf16x8 bv = *(const bf16x8*)&Vs[(n * 16 + (lane & 15)) * 64 + co];
        acc[n] = mfma16(a, bv, acc[n]);
      }
      acc[4] = mfma16(a, ones_frag, acc[4]);
    }
  }
  float* dst = kvp + (size_t)blk * 64 * 64;
  const int d0 = wave * 16 + ((lane >> 4) << 2);
#pragma unroll
  for (int n = 0; n < 4; ++n)
#pragma unroll
    for (int i = 0; i < 4; ++i)
      dst[(d0 + i) * 64 + n * 16 + (lane & 15)] = acc[n][i];
  if ((lane & 15) == 0) {
#pragma unroll
    for (int i = 0; i < 4; ++i) sumkp[(size_t)blk * 64 + d0 + i] = acc[4][i];
  }
}

// ---------------- kv reduce ----------------

__global__ __launch_bounds__(256) void k_kvred(const float* __restrict__ kvp,
                                               const float* __restrict__ sumkp,
                                               unsigned short* __restrict__ kvsk) {
  const int bh = blockIdx.x, tid = threadIdx.x;
  const float* src = kvp + (size_t)bh * 8 * 4096;
  unsigned short* dst = kvsk + (size_t)bh * 80 * 64;
#pragma unroll
  for (int it = 0; it < 16; ++it) {
    const int idx = tid + it * 256;
    const int e = idx >> 6, d = idx & 63;
    float s = 0.f;
#pragma unroll
    for (int c = 0; c < 8; ++c) s += src[c * 4096 + d * 64 + e];
    dst[idx] = f2bf(s);
  }
#pragma unroll
  for (int it = 0; it < 4; ++it) {
    const int idx = tid + it * 256;
    const int e2 = idx >> 6, d = idx & 63;
    float v = 0.f;
    if (e2 == 0) {
#pragma unroll
      for (int c = 0; c < 8; ++c) v += sumkp[(size_t)(bh * 8 + c) * 64 + d];
    }
    dst[64 * 64 + idx] = f2bf(v);
  }
}

// ---------------- numerator/denominator/divide ----------------

__global__ __launch_bounds__(256) void k_numer(const unsigned short* __restrict__ qb,
                                               const unsigned short* __restrict__ kvsk,
                                               unsigned short* __restrict__ yb) {
  __shared__ unsigned short Bs[80 * 64];
  const int bh = blockIdx.y;
  const int b = bh >> 4, h = bh & 15;
  const int n0 = blockIdx.x << 7;
  const int tid = threadIdx.x, lane = tid & 63, wave = tid >> 6;
  {
    const uint4* src = (const uint4*)(kvsk + (size_t)bh * 80 * 64);
    uint4* dst = (uint4*)Bs;
    for (int i = tid; i < 640; i += 256) dst[i ^ ((i >> 3) & 7)] = src[i];
  }
  __syncthreads();

  const int ko = (lane >> 4) << 3;
  const int rx = (lane & 7) << 3;
  f32x4 acc[2][5] = {};
  const unsigned short* qrow =
      qb + (size_t)(b * 4096 + n0 + wave * 32 + (lane & 15)) * 1024 + h * 64;
#pragma unroll
  for (int kk = 0; kk < 2; ++kk) {
    bf16x8 a[2], bb[5];
#pragma unroll
    for (int m = 0; m < 2; ++m)
      a[m] = *(const bf16x8*)(qrow + (size_t)m * 16 * 1024 + ko + kk * 32);
#pragma unroll
    for (int n = 0; n < 5; ++n)
      bb[n] = *(const bf16x8*)&Bs[(n * 16 + (lane & 15)) * 64 + ((ko + kk * 32) ^ rx)];
#pragma unroll
    for (int m = 0; m < 2; ++m)
#pragma unroll
      for (int n = 0; n < 5; ++n)
        acc[m][n] = mfma16(a[m], bb[n], acc[m][n]);
  }

  const int rbase = b * 4096 + n0 + wave * 32 + ((lane >> 4) << 2);
#pragma unroll
  for (int m = 0; m < 2; ++m) {
    f32x4 inv;
#pragma unroll
    for (int i = 0; i < 4; ++i) {
      float den = __shfl(acc[m][4][i], lane & 48);
      inv[i] = __builtin_amdgcn_rcpf(den);
    }
#pragma unroll
    for (int n = 0; n < 4; ++n) {
      const int col = h * 64 + n * 16 + (lane & 15);
#pragma unroll
      for (int i = 0; i < 4; ++i)
        yb[(size_t)(rbase + m * 16 + i) * 1024 + col] = f2bf(acc[m][n][i] * inv[i]);
    }
  }
}

// ---------------- launch ----------------

extern "C" void kernel_launch(void* const* d_in, const int* in_sizes, int n_in,
                              void* d_out, int out_size, void* d_ws, size_t ws_size,
                              hipStream_t stream) {
  const float* x = (const float*)d_in[0];
  const float* w_qkv = (const float*)d_in[1];
  const float* w_proj = (const float*)d_in[2];
  const float* b_proj = (const float*)d_in[3];
  float* out = (float*)d_out;
  char* ws = (char*)d_ws;

  unsigned short* xb = (unsigned short*)(ws);                   // 33,554,432 B (reused as yb)
  unsigned short* wqkvT = (unsigned short*)(ws + 33554432);     //  6,291,456 B (reused as sumkp)
  unsigned short* wprojT = (unsigned short*)(ws + 39845888);    //  2,097,152 B
  unsigned short* qb = (unsigned short*)(ws + 41943040);        // 33,554,432 B
  unsigned short* kT = (unsigned short*)(ws + 75497472);        // 33,554,432 B
  unsigned short* vT = (unsigned short*)(ws + 109051904);       // 33,554,432 B
  float* kvp = (float*)(ws + 142606336);                        //  8,388,608 B
  unsigned short* kvsk = (unsigned short*)(ws + 151011328);     //    655,360 B
  unsigned short* yb = xb;                 // xb dead after GEMM1
  float* sumkp = (float*)wqkvT;            // wqkvT dead after GEMM1 (512*64*4 B)

  k_cvt_x<<<2048, 256, 0, stream>>>(x, xb, 4 * 4096 * 1024);
  k_cvt_t<<<dim3(96, 32), 256, 0, stream>>>(w_qkv, wqkvT, 1024, 3072);
  k_cvt_t<<<dim3(32, 32), 256, 0, stream>>>(w_proj, wprojT, 1024, 1024);
  k_gemmq<<<768, 512, 65536, stream>>>(xb, wqkvT, qb, kT, vT);
  k_kvpart<<<512, 256, 0, stream>>>(kT, vT, kvp, sumkp);
  k_kvred<<<64, 256, 0, stream>>>(kvp, sumkp, kvsk);
  k_numer<<<dim3(32, 64), 256, 0, stream>>>(qb, kvsk, yb);
  k_gemmp<<<512, 512, 49152, stream>>>(yb, wprojT, b_proj, out);
}

// Round 9
// 218.943 us; speedup vs baseline: 1.1957x; 1.0370x over previous
//
#include <hip/hip_runtime.h>

typedef __bf16 bf16x8 __attribute__((ext_vector_type(8)));
typedef float f32x4 __attribute__((ext_vector_type(4)));

typedef const unsigned int __attribute__((address_space(1)))* gas_p;
typedef unsigned int __attribute__((address_space(3)))* las_p;

__device__ __forceinline__ void gload_lds16(const void* g, void* l) {
  __builtin_amdgcn_global_load_lds((gas_p)g, (las_p)l, 16, 0, 0);
}

__device__ __forceinline__ unsigned short f2bf(float f) {
  union { float f; unsigned int u; } x; x.f = f;
  unsigned int r = x.u + 0x7fffu + ((x.u >> 16) & 1u);
  return (unsigned short)(r >> 16);
}
__device__ __forceinline__ float elu1(float x) {
  return x > 0.f ? x + 1.f : __expf(x);
}
__device__ __forceinline__ f32x4 mfma16(bf16x8 a, bf16x8 b, f32x4 c) {
  return __builtin_amdgcn_mfma_f32_16x16x32_bf16(a, b, c, 0, 0, 0);
}

#define BAR() __builtin_amdgcn_s_barrier()
#define VMW0() asm volatile("s_waitcnt vmcnt(0)" ::: "memory")

// ---------------- converts ----------------

__global__ __launch_bounds__(256) void k_cvt_x(const float* __restrict__ x,
                                               unsigned short* __restrict__ xb, int n) {
  int i = (blockIdx.x * 256 + threadIdx.x) * 4;
  const int stride = gridDim.x * 256 * 4;
  for (; i < n; i += stride) {
    float4 v = *(const float4*)(x + i);
    union { unsigned short u[4]; uint2 q; } pk;
    pk.u[0] = f2bf(v.x); pk.u[1] = f2bf(v.y); pk.u[2] = f2bf(v.z); pk.u[3] = f2bf(v.w);
    *(uint2*)(xb + i) = pk.q;
  }
}

__global__ __launch_bounds__(256) void k_cvt_t(const float* __restrict__ w,
                                               unsigned short* __restrict__ wT,
                                               int R, int Cc) {
  __shared__ float t[32][33];
  const int j0 = blockIdx.x * 32, i0 = blockIdx.y * 32;
  const int tx = threadIdx.x & 31, ty = threadIdx.x >> 5;
#pragma unroll
  for (int k = 0; k < 4; ++k)
    t[ty + 8 * k][tx] = w[(size_t)(i0 + ty + 8 * k) * Cc + j0 + tx];
  __syncthreads();
#pragma unroll
  for (int k = 0; k < 4; ++k)
    wT[(size_t)(j0 + ty + 8 * k) * R + i0 + tx] = f2bf(t[tx][ty + 8 * k]);
}

// ---------------- 256x256 GEMM, ONE barrier per K-tile (overlap LDS-read & MFMA) ------
// LDS: 4 slots/operand of [256 rows][32 K] bf16. pair p in slot p&3; tile t = pairs
// {2t,2t+1} = slot-pair {0,1} or {2,3}, alternating. Per tile: stage tile t+1 into the
// other slot-pair; 24 ds_read_b128 + 64 MFMA compiler-interleaved (counted lgkmcnt);
// VMW0 drains the 8 stage loads (in flight ~1 full tile); single BAR publishes/protects.
// Swizzle: read col ^= ((row>>1)&3)<<3 elems; DMA source col pre-swizzled (rule 21).

template <int EPI>
__global__ __launch_bounds__(512, 2) void k_gemm256(
    const unsigned short* __restrict__ A, const unsigned short* __restrict__ BT, int NBX,
    unsigned short* __restrict__ qb, unsigned short* __restrict__ kT,
    unsigned short* __restrict__ vT, const float* __restrict__ bias,
    float* __restrict__ out) {
  extern __shared__ unsigned short lds[];
  unsigned short* Asb = lds;           // 4 slots x 8192 elems (64 KiB)
  unsigned short* Bsb = lds + 32768;   // 4 slots x 8192 elems (64 KiB)

  const int tid = threadIdx.x, lane = tid & 63, wave = tid >> 6;
  const int wm = wave >> 2, wn = wave & 3;
  int bid = blockIdx.x;
  { const int cpx = (int)gridDim.x >> 3; bid = (bid & 7) * cpx + (bid >> 3); }
  const int bx = bid % NBX, by = bid / NBX;
  const size_t bm0 = (size_t)by << 8, bn0 = (size_t)bx << 8;

  const int srow = (wave << 4) + (lane >> 2);
  const int gscol = ((lane & 3) << 3) ^ (((srow >> 1) & 3) << 3);
  const unsigned short* Ag0 = A + (bm0 + srow) * 1024 + gscol;
  const unsigned short* Bg0 = BT + (bn0 + srow) * 1024 + gscol;
  const int lws = wave << 9;

  auto stageA = [&](int pair) {
    const unsigned short* g_ = Ag0 + (pair << 5);
    unsigned short* l_ = Asb + ((pair & 3) << 13) + lws;
    gload_lds16(g_, l_);
    gload_lds16(g_ + 128 * 1024, l_ + 4096);
  };
  auto stageB = [&](int pair) {
    const unsigned short* g_ = Bg0 + (pair << 5);
    unsigned short* l_ = Bsb + ((pair & 3) << 13) + lws;
    gload_lds16(g_, l_);
    gload_lds16(g_ + 128 * 1024, l_ + 4096);
  };

  const int q8 = ((lane >> 4) << 3) ^ (((lane >> 1) & 3) << 3);
  const int ar_base = (wm << 7) + (lane & 15);
  const int br_base = (wn << 6) + (lane & 15);

  f32x4 acc[8][4] = {};  // [rh*4+mi][n]

  // prologue: stage tile 0 (pairs 0,1 -> slots 0,1)
  stageA(0); stageB(0); stageA(1); stageB(1);
  VMW0();
  BAR();

#pragma unroll
  for (int t = 0; t < 16; ++t) {
    const int o0 = ((2 * t) & 3) << 13, o1 = ((2 * t + 1) & 3) << 13;

    // stage tile t+1 into the other slot-pair (safe: last reader synced at prev BAR)
    if (t < 15) { stageA(2 * t + 2); stageB(2 * t + 2); stageA(2 * t + 3); stageB(2 * t + 3); }

    bf16x8 a0[4], a1[4], b0[4], b1[4];
#pragma unroll
    for (int mi = 0; mi < 4; ++mi)
      a0[mi] = *(const bf16x8*)&Asb[o0 + ((ar_base + mi * 16) << 5) + q8];
#pragma unroll
    for (int n = 0; n < 4; ++n)
      b0[n] = *(const bf16x8*)&Bsb[o0 + ((br_base + n * 16) << 5) + q8];
#pragma unroll
    for (int mi = 0; mi < 4; ++mi)
      a1[mi] = *(const bf16x8*)&Asb[o1 + ((ar_base + mi * 16) << 5) + q8];
#pragma unroll
    for (int n = 0; n < 4; ++n)
      b1[n] = *(const bf16x8*)&Bsb[o1 + ((br_base + n * 16) << 5) + q8];
    __builtin_amdgcn_s_setprio(1);
#pragma unroll
    for (int mi = 0; mi < 4; ++mi)
#pragma unroll
      for (int n = 0; n < 4; ++n) acc[mi][n] = mfma16(a0[mi], b0[n], acc[mi][n]);
#pragma unroll
    for (int mi = 0; mi < 4; ++mi)
#pragma unroll
      for (int n = 0; n < 4; ++n) acc[mi][n] = mfma16(a1[mi], b1[n], acc[mi][n]);
    __builtin_amdgcn_s_setprio(0);

    // second row-half
#pragma unroll
    for (int mi = 0; mi < 4; ++mi)
      a0[mi] = *(const bf16x8*)&Asb[o0 + ((ar_base + 64 + mi * 16) << 5) + q8];
#pragma unroll
    for (int mi = 0; mi < 4; ++mi)
      a1[mi] = *(const bf16x8*)&Asb[o1 + ((ar_base + 64 + mi * 16) << 5) + q8];
    __builtin_amdgcn_s_setprio(1);
#pragma unroll
    for (int mi = 0; mi < 4; ++mi)
#pragma unroll
      for (int n = 0; n < 4; ++n) acc[4 + mi][n] = mfma16(a0[mi], b0[n], acc[4 + mi][n]);
#pragma unroll
    for (int mi = 0; mi < 4; ++mi)
#pragma unroll
      for (int n = 0; n < 4; ++n) acc[4 + mi][n] = mfma16(a1[mi], b1[n], acc[4 + mi][n]);
    __builtin_amdgcn_s_setprio(0);

    if (t < 15) VMW0();  // drain this tile's 8 stage loads (issued ~1 tile ago)
    BAR();               // publish t+1 data; protect slot-pair t from next stage
  }

  // ---- epilogue ----
  const int rbase = (int)bm0 + (wm << 7) + ((lane >> 4) << 2);
  const int cbase = (int)bn0 + (wn << 6) + (lane & 15);
  if constexpr (EPI == 0) {
    const int reg3 = (int)(bn0 >> 10);  // 0=q 1=k 2=v, uniform per block
#pragma unroll
    for (int m = 0; m < 8; ++m) {
      const int rb = rbase + m * 16;
#pragma unroll
      for (int n = 0; n < 4; ++n) {
        const int col = cbase + n * 16;
        if (reg3 == 0) {
#pragma unroll
          for (int i = 0; i < 4; ++i)
            qb[(size_t)(rb + i) * 1024 + col] = f2bf(elu1(acc[m][n][i]));
        } else {
          const int jc = col & 1023, h = jc >> 6, d = jc & 63;
          const int b_ = rb >> 12, n_ = rb & 4095;
          union { unsigned short u[4]; uint2 q; } pk;
          if (reg3 == 1) {
#pragma unroll
            for (int i = 0; i < 4; ++i) pk.u[i] = f2bf(elu1(acc[m][n][i]));
          } else {
#pragma unroll
            for (int i = 0; i < 4; ++i) pk.u[i] = f2bf(acc[m][n][i]);
          }
          unsigned short* dst = (reg3 == 1) ? kT : vT;
          *(uint2*)(dst + ((size_t)((b_ * 16 + h) * 64 + d) * 4096 + n_)) = pk.q;
        }
      }
    }
  } else {
#pragma unroll
    for (int n = 0; n < 4; ++n) {
      const int col = cbase + n * 16;
      const float bc = bias[col];
#pragma unroll
      for (int m = 0; m < 8; ++m) {
        const int rb = rbase + m * 16;
#pragma unroll
        for (int i = 0; i < 4; ++i)
          out[(size_t)(rb + i) * 1024 + col] = acc[m][n][i] + bc;
      }
    }
  }
}

// ---------------- kv partial (+ fused sum_k via ones-column) ----------------

__global__ __launch_bounds__(256) void k_kvpart(const unsigned short* __restrict__ kT,
                                                const unsigned short* __restrict__ vT,
                                                float* __restrict__ kvp,
                                                float* __restrict__ sumkp) {
  __shared__ unsigned short Ks[64 * 64];
  __shared__ unsigned short Vs[64 * 64];
  const int blk = blockIdx.x;
  const int bh = blk >> 3, ch = blk & 7;
  const int tid = threadIdx.x, lane = tid & 63, wave = tid >> 6;
  const unsigned short* kb = kT + (size_t)bh * 64 * 4096;
  const unsigned short* vb = vT + (size_t)bh * 64 * 4096;
  const int n0 = ch * 512;
  const int lrow = lane >> 3;
  const int lcolz = (((lane & 7) ^ (lane >> 3)) << 3);
  f32x4 acc[5] = {};

  bf16x8 ones_frag;
  {
    unsigned short o = ((lane & 15) == 0) ? (unsigned short)0x3F80 : (unsigned short)0;
    union { unsigned short u[8]; bf16x8 v; } c;
#pragma unroll
    for (int i = 0; i < 8; ++i) c.u[i] = o;
    ones_frag = c.v;
  }

  const int rxor = (lane & 7) << 3;
  const int col0 = (((lane >> 4) << 3)) ^ rxor;
  const int col1 = ((32 + ((lane >> 4) << 3))) ^ rxor;

  for (int ks = 0; ks < 512; ks += 64) {
    __syncthreads();
#pragma unroll
    for (int i = 0; i < 2; ++i) {
      const int c = i * 4 + wave;
      gload_lds16(kb + (size_t)(c * 8 + lrow) * 4096 + n0 + ks + lcolz, &Ks[c * 512]);
      gload_lds16(vb + (size_t)(c * 8 + lrow) * 4096 + n0 + ks + lcolz, &Vs[c * 512]);
    }
    __syncthreads();
    const int ar = wave * 16 + (lane & 15);
#pragma unroll
    for (int kk = 0; kk < 2; ++kk) {
      const int co = kk ? col1 : col0;
      bf16x8 a = *(const bf16x8*)&Ks[ar * 64 + co];
#pragma unroll
      for (int n = 0; n < 4; ++n) {
        bf16x8 bv = *(const bf16x8*)&Vs[(n * 16 + (lane & 15)) * 64 + co];
        acc[n] = mfma16(a, bv, acc[n]);
      }
      acc[4] = mfma16(a, ones_frag, acc[4]);
    }
  }
  float* dst = kvp + (size_t)blk * 64 * 64;
  const int d0 = wave * 16 + ((lane >> 4) << 2);
#pragma unroll
  for (int n = 0; n < 4; ++n)
#pragma unroll
    for (int i = 0; i < 4; ++i)
      dst[(d0 + i) * 64 + n * 16 + (lane & 15)] = acc[n][i];
  if ((lane & 15) == 0) {
#pragma unroll
    for (int i = 0; i < 4; ++i) sumkp[(size_t)blk * 64 + d0 + i] = acc[4][i];
  }
}

// ---------------- kv reduce ----------------

__global__ __launch_bounds__(256) void k_kvred(const float* __restrict__ kvp,
                                               const float* __restrict__ sumkp,
                                               unsigned short* __restrict__ kvsk) {
  const int bh = blockIdx.x, tid = threadIdx.x;
  const float* src = kvp + (size_t)bh * 8 * 4096;
  unsigned short* dst = kvsk + (size_t)bh * 80 * 64;
#pragma unroll
  for (int it = 0; it < 16; ++it) {
    const int idx = tid + it * 256;
    const int e = idx >> 6, d = idx & 63;
    float s = 0.f;
#pragma unroll
    for (int c = 0; c < 8; ++c) s += src[c * 4096 + d * 64 + e];
    dst[idx] = f2bf(s);
  }
#pragma unroll
  for (int it = 0; it < 4; ++it) {
    const int idx = tid + it * 256;
    const int e2 = idx >> 6, d = idx & 63;
    float v = 0.f;
    if (e2 == 0) {
#pragma unroll
      for (int c = 0; c < 8; ++c) v += sumkp[(size_t)(bh * 8 + c) * 64 + d];
    }
    dst[64 * 64 + idx] = f2bf(v);
  }
}

// ---------------- numerator/denominator/divide ----------------

__global__ __launch_bounds__(256) void k_numer(const unsigned short* __restrict__ qb,
                                               const unsigned short* __restrict__ kvsk,
                                               unsigned short* __restrict__ yb) {
  __shared__ unsigned short Bs[80 * 64];
  const int bh = blockIdx.y;
  const int b = bh >> 4, h = bh & 15;
  const int n0 = blockIdx.x << 7;
  const int tid = threadIdx.x, lane = tid & 63, wave = tid >> 6;
  {
    const uint4* src = (const uint4*)(kvsk + (size_t)bh * 80 * 64);
    uint4* dst = (uint4*)Bs;
    for (int i = tid; i < 640; i += 256) dst[i ^ ((i >> 3) & 7)] = src[i];
  }
  __syncthreads();

  const int ko = (lane >> 4) << 3;
  const int rx = (lane & 7) << 3;
  f32x4 acc[2][5] = {};
  const unsigned short* qrow =
      qb + (size_t)(b * 4096 + n0 + wave * 32 + (lane & 15)) * 1024 + h * 64;
#pragma unroll
  for (int kk = 0; kk < 2; ++kk) {
    bf16x8 a[2], bb[5];
#pragma unroll
    for (int m = 0; m < 2; ++m)
      a[m] = *(const bf16x8*)(qrow + (size_t)m * 16 * 1024 + ko + kk * 32);
#pragma unroll
    for (int n = 0; n < 5; ++n)
      bb[n] = *(const bf16x8*)&Bs[(n * 16 + (lane & 15)) * 64 + ((ko + kk * 32) ^ rx)];
#pragma unroll
    for (int m = 0; m < 2; ++m)
#pragma unroll
      for (int n = 0; n < 5; ++n)
        acc[m][n] = mfma16(a[m], bb[n], acc[m][n]);
  }

  const int rbase = b * 4096 + n0 + wave * 32 + ((lane >> 4) << 2);
#pragma unroll
  for (int m = 0; m < 2; ++m) {
    f32x4 inv;
#pragma unroll
    for (int i = 0; i < 4; ++i) {
      float den = __shfl(acc[m][4][i], lane & 48);
      inv[i] = __builtin_amdgcn_rcpf(den);
    }
#pragma unroll
    for (int n = 0; n < 4; ++n) {
      const int col = h * 64 + n * 16 + (lane & 15);
#pragma unroll
      for (int i = 0; i < 4; ++i)
        yb[(size_t)(rbase + m * 16 + i) * 1024 + col] = f2bf(acc[m][n][i] * inv[i]);
    }
  }
}

// ---------------- launch ----------------

extern "C" void kernel_launch(void* const* d_in, const int* in_sizes, int n_in,
                              void* d_out, int out_size, void* d_ws, size_t ws_size,
                              hipStream_t stream) {
  const float* x = (const float*)d_in[0];
  const float* w_qkv = (const float*)d_in[1];
  const float* w_proj = (const float*)d_in[2];
  const float* b_proj = (const float*)d_in[3];
  float* out = (float*)d_out;
  char* ws = (char*)d_ws;

  unsigned short* xb = (unsigned short*)(ws);                   // 33,554,432 B (reused as yb)
  unsigned short* wqkvT = (unsigned short*)(ws + 33554432);     //  6,291,456 B (reused as sumkp)
  unsigned short* wprojT = (unsigned short*)(ws + 39845888);    //  2,097,152 B
  unsigned short* qb = (unsigned short*)(ws + 41943040);        // 33,554,432 B
  unsigned short* kT = (unsigned short*)(ws + 75497472);        // 33,554,432 B
  unsigned short* vT = (unsigned short*)(ws + 109051904);       // 33,554,432 B
  float* kvp = (float*)(ws + 142606336);                        //  8,388,608 B
  unsigned short* kvsk = (unsigned short*)(ws + 151011328);     //    655,360 B
  unsigned short* yb = xb;                 // xb dead after GEMM1
  float* sumkp = (float*)wqkvT;            // wqkvT dead after GEMM1 (512*64*4 B)

  k_cvt_x<<<2048, 256, 0, stream>>>(x, xb, 4 * 4096 * 1024);
  k_cvt_t<<<dim3(96, 32), 256, 0, stream>>>(w_qkv, wqkvT, 1024, 3072);
  k_cvt_t<<<dim3(32, 32), 256, 0, stream>>>(w_proj, wprojT, 1024, 1024);
  k_gemm256<0><<<768, 512, 131072, stream>>>(xb, wqkvT, 12, qb, kT, vT, nullptr, nullptr);
  k_kvpart<<<512, 256, 0, stream>>>(kT, vT, kvp, sumkp);
  k_kvred<<<64, 256, 0, stream>>>(kvp, sumkp, kvsk);
  k_numer<<<dim3(32, 64), 256, 0, stream>>>(qb, kvsk, yb);
  k_gemm256<1><<<256, 512, 131072, stream>>>(yb, wprojT, 4, nullptr, nullptr, nullptr,
                                             b_proj, out);
}